// Round 24
// baseline (348.510 us; speedup 1.0000x reference)
//
#include <hip/hip_runtime.h>

#define HH 256
#define WW 256
#define HWSZ (HH*WW)
#define CH 32

typedef __attribute__((ext_vector_type(8))) short bfrag;   // 8 bf16 = 4 VGPRs
typedef __attribute__((ext_vector_type(4))) float f32x4;

__device__ __forceinline__ float lrelu_f(float x){ return x >= 0.f ? x : 0.2f*x; }

__device__ __forceinline__ unsigned short bf16_rne(float f){
    unsigned int u = __float_as_uint(f);
    unsigned int r = (u + 0x7fffu + ((u >> 16) & 1u)) >> 16;
    return (unsigned short)r;
}
__device__ __forceinline__ float bf16_to_f(unsigned short h){
    return __uint_as_float(((unsigned int)h) << 16);
}

// ============================ fp32 fallback kernels =========================

__global__ __launch_bounds__(256) void conv1x1_kernel(
    const float* __restrict__ s, const float* __restrict__ l,
    const float* __restrict__ w, const float* __restrict__ bias,
    float* __restrict__ y)
{
    int gid = blockIdx.x*256 + threadIdx.x;
    int b = gid >> 16;
    int pix = gid & (HWSZ-1);
    const float* sp = s + (size_t)b*CH*HWSZ + pix;
    const float* lp = l + (size_t)b*CH*HWSZ + pix;
    float acc[CH];
    #pragma unroll
    for (int o=0;o<CH;++o) acc[o] = bias[o];
    for (int c=0;c<CH;++c) {
        float v = sp[(size_t)c*HWSZ];
        #pragma unroll
        for (int o=0;o<CH;++o) acc[o] += w[o*64+c]*v;
    }
    for (int c=0;c<CH;++c) {
        float v = lp[(size_t)c*HWSZ];
        #pragma unroll
        for (int o=0;o<CH;++o) acc[o] += w[o*64+32+c]*v;
    }
    float* yp = y + (size_t)b*CH*HWSZ + pix;
    #pragma unroll
    for (int o=0;o<CH;++o) yp[(size_t)o*HWSZ] = acc[o];
}

template<int NP>
__global__ __launch_bounds__(256) void conv3x3_kernel(
    const float* __restrict__ x0, const float* __restrict__ x1,
    const float* __restrict__ w, const float* __restrict__ bias,
    float* __restrict__ y, int relu)
{
    int gid = blockIdx.x*256 + threadIdx.x;
    int b = gid >> 16;
    int pix = gid & (HWSZ-1);
    int h = pix >> 8, cw = pix & 255;
    const int CIN = 32*NP;
    float acc[CH];
    #pragma unroll
    for (int o=0;o<CH;++o) acc[o] = bias[o];
    #pragma unroll
    for (int p=0;p<NP;++p) {
        const float* src = (p==0) ? x0 : x1;
        const float* xb = src + (size_t)b*CH*HWSZ;
        for (int c=0;c<CH;++c) {
            const float* xp = xb + (size_t)c*HWSZ;
            float v[9];
            #pragma unroll
            for (int t=0;t<9;++t) {
                int hh = h + t/3 - 1;
                int wx = cw + t%3 - 1;
                v[t] = (hh>=0 && hh<HH && wx>=0 && wx<WW) ? xp[hh*WW+wx] : 0.f;
            }
            const float* wp = w + (size_t)(p*32 + c)*9;
            #pragma unroll
            for (int o=0;o<CH;++o) {
                #pragma unroll
                for (int t=0;t<9;++t)
                    acc[o] += wp[(size_t)o*CIN*9 + t] * v[t];
            }
        }
    }
    float* yp = y + (size_t)b*CH*HWSZ + pix;
    #pragma unroll
    for (int o=0;o<CH;++o)
        yp[(size_t)o*HWSZ] = relu ? lrelu_f(acc[o]) : acc[o];
}

__global__ __launch_bounds__(256) void up2_kernel(
    const float* __restrict__ x, float* __restrict__ y)
{
    int gid = blockIdx.x*256 + threadIdx.x;
    int ow = gid & 255;
    int oh = (gid >> 8) & 255;
    int bc = gid >> 16;
    const int Hin = 128, Win = 128;
    float cy = (oh + 0.5f)*0.5f - 0.5f;
    float cx = (ow + 0.5f)*0.5f - 0.5f;
    cy = fminf(fmaxf(cy, 0.f), (float)(Hin-1));
    cx = fminf(fmaxf(cx, 0.f), (float)(Win-1));
    int y0 = (int)floorf(cy);
    int x0 = (int)floorf(cx);
    int y1 = min(y0+1, Hin-1);
    int x1 = min(x0+1, Win-1);
    float ty = cy - (float)y0, tx = cx - (float)x0;
    const float* xp = x + (size_t)bc*Hin*Win;
    float v00 = xp[y0*Win+x0], v01 = xp[y0*Win+x1];
    float v10 = xp[y1*Win+x0], v11 = xp[y1*Win+x1];
    float v = v00*(1.f-ty)*(1.f-tx) + v01*(1.f-ty)*tx + v10*ty*(1.f-tx) + v11*ty*tx;
    y[gid] = 2.0f*v;
}

__global__ __launch_bounds__(256) void dcn_off_kernel(
    const float* __restrict__ x, const float* __restrict__ w,
    const float* __restrict__ bias, float* __restrict__ om,
    int r0, int rows)
{
    int b = blockIdx.x / rows;
    int rr = blockIdx.x % rows;
    int cw = threadIdx.x;
    int h = r0 + rr;
    int oc0 = blockIdx.y*24;
    const float* xb = x + (size_t)b*CH*HWSZ;
    float* omb = om + (size_t)b*216*rows*WW;
    float acc[24];
    #pragma unroll
    for (int j=0;j<24;++j) acc[j] = bias[oc0+j];
    for (int c=0;c<32;++c) {
        const float* xp = xb + (size_t)c*HWSZ;
        float v[9];
        #pragma unroll
        for (int t=0;t<9;++t) {
            int hh = h + t/3 - 1;
            int wx = cw + t%3 - 1;
            v[t] = (hh>=0 && hh<HH && wx>=0 && wx<WW) ? xp[hh*WW+wx] : 0.f;
        }
        const float* wpp = w + (size_t)c*9;
        #pragma unroll
        for (int j=0;j<24;++j) {
            #pragma unroll
            for (int t=0;t<9;++t)
                acc[j] += wpp[(size_t)(oc0+j)*288 + t] * v[t];
        }
    }
    #pragma unroll
    for (int j=0;j<24;++j)
        omb[(size_t)(oc0+j)*rows*WW + (size_t)rr*WW + cw] = acc[j];
}

// Legacy full sampling+einsum kernel (fallback path).
__global__ __launch_bounds__(256) void dcn_kernel(
    const float* __restrict__ x, const float* __restrict__ om,
    const float* __restrict__ w, const float* __restrict__ bias,
    float* __restrict__ y, int r0, int rows)
{
    const int b  = blockIdx.z;
    const int os = blockIdx.y;
    const int rowsWW = rows*WW;
    int rr = blockIdx.x;
    int cw = threadIdx.x;
    int h = r0 + rr;
    const float* xb  = x  + (size_t)b*CH*HWSZ;
    const float* omb = om + (size_t)b*216*rowsWW;
    int ppos = rr*WW + cw;
    int ob = os*16;

    float acc[16];
    #pragma unroll
    for (int o=0;o<16;++o) acc[o] = bias[ob+o];

    for (int g=0; g<8; ++g) {
        const float* xg = xb + (size_t)g*4*HWSZ;
        #pragma unroll
        for (int k=0;k<9;++k) {
            int oc = g*9+k;
            float dy = omb[(size_t)oc*rowsWW + ppos];
            float dx = omb[(size_t)(72+oc)*rowsWW + ppos];
            float mm = omb[(size_t)(144+oc)*rowsWW + ppos];
            mm = 1.f/(1.f + __expf(-mm));
            float py = dy + (float)(h + k/3 - 1);
            float px = dx + (float)(cw + k%3 - 1);
            float y0f = floorf(py), x0f = floorf(px);
            int yi = (int)y0f, xi = (int)x0f;
            float ty = py - y0f, tx = px - x0f;
            float w00 = (1.f-ty)*(1.f-tx), w01 = (1.f-ty)*tx;
            float w10 = ty*(1.f-tx),       w11 = ty*tx;
            int yc0 = min(max(yi,0),HH-1),   yc1 = min(max(yi+1,0),HH-1);
            int xc0 = min(max(xi,0),WW-1),   xc1 = min(max(xi+1,0),WW-1);
            bool vy0 = (yi>=0)&&(yi<HH),     vy1 = (yi+1>=0)&&(yi+1<HH);
            bool vx0 = (xi>=0)&&(xi<WW),     vx1 = (xi+1>=0)&&(xi+1<WW);
            float f00 = (vy0&&vx0)? w00*mm : 0.f;
            float f01 = (vy0&&vx1)? w01*mm : 0.f;
            float f10 = (vy1&&vx0)? w10*mm : 0.f;
            float f11 = (vy1&&vx1)? w11*mm : 0.f;
            int i00 = yc0*WW+xc0, i01 = yc0*WW+xc1;
            int i10 = yc1*WW+xc0, i11 = yc1*WW+xc1;
            #pragma unroll
            for (int c=0;c<4;++c) {
                const float* xc = xg + (size_t)c*HWSZ;
                float val = xc[i00]*f00 + xc[i01]*f01 + xc[i10]*f10 + xc[i11]*f11;
                const float* wpp = w + (size_t)(g*4+c)*9 + k;
                #pragma unroll
                for (int o=0;o<16;++o)
                    acc[o] += wpp[(size_t)(ob+o)*288] * val;
            }
        }
    }

    float* yb = y + (size_t)(b*CH + ob)*HWSZ + (size_t)h*WW;
    #pragma unroll
    for (int o=0;o<16;++o)
        yb[(size_t)o*HWSZ + cw] = lrelu_f(acc[o]);
}

// ============================ bf16 MFMA path ================================

__global__ __launch_bounds__(256) void pack_w_bf16(
    const float* __restrict__ dow, unsigned short* __restrict__ wp)
{
    int gid = blockIdx.x*256 + threadIdx.x;   // 9*14*64
    if (gid >= 9*14*64) return;
    int l = gid & 63;
    int rest = gid >> 6;
    int nt = rest % 14;
    int ks = rest / 14;
    int oc = nt*16 + (l & 15);
    int c0 = 8*(l >> 4);
    unsigned short outv[8];
    #pragma unroll
    for (int j=0;j<8;++j) {
        float v = (oc < 216) ? dow[(size_t)oc*288 + (size_t)(c0+j)*9 + ks] : 0.f;
        outv[j] = bf16_rne(v);
    }
    unsigned short* dst = wp + (size_t)gid*8;
    #pragma unroll
    for (int j=0;j<8;++j) dst[j] = outv[j];
}

__global__ __launch_bounds__(256) void pack_conv_hl(
    const float* __restrict__ w, unsigned short* __restrict__ wphi,
    unsigned short* __restrict__ wplo, int TAPS, int F)
{
    int total = TAPS*F*2*64;
    int gid = blockIdx.x*256 + threadIdx.x;
    if (gid >= total) return;
    int l = gid & 63;
    int q = gid >> 6;
    int nt = q & 1;
    int p = q >> 1;
    int f = p % F;
    int ks = p / F;
    int oc = nt*16 + (l & 15);
    int CIN = F*32;
    unsigned short hv[8], lv[8];
    #pragma unroll
    for (int j=0;j<8;++j) {
        int c = f*32 + (l>>4)*8 + j;
        float v = w[(size_t)oc*CIN*TAPS + (size_t)c*TAPS + ks];
        unsigned short h = bf16_rne(v);
        hv[j] = h;
        lv[j] = bf16_rne(v - bf16_to_f(h));
    }
    unsigned short* dh = wphi + (size_t)gid*8;
    unsigned short* dl = wplo + (size_t)gid*8;
    #pragma unroll
    for (int j=0;j<8;++j) { dh[j] = hv[j]; dl[j] = lv[j]; }
}

// Pack dcn einsum weights for the val-GEMM: K = (g*9+k)*4 + c, hi/lo.
__global__ __launch_bounds__(256) void pack_wg(
    const float* __restrict__ dcw, unsigned short* __restrict__ wgh,
    unsigned short* __restrict__ wgl)
{
    int gid = blockIdx.x*256 + threadIdx.x;   // 9*2*64 = 1152
    if (gid >= 1152) return;
    int l = gid & 63;
    int q = gid >> 6;
    int nt = q & 1;
    int ks = q >> 1;
    int oc = nt*16 + (l & 15);
    unsigned short hv[8], lv[8];
    #pragma unroll
    for (int j=0;j<8;++j) {
        int K = ks*32 + (l>>4)*8 + j;
        int g = K/36;
        int rem = K - g*36;
        int kk = rem >> 2;
        int c = rem & 3;
        float v = dcw[(size_t)oc*288 + (size_t)(g*4+c)*9 + kk];
        unsigned short h = bf16_rne(v);
        hv[j] = h;
        lv[j] = bf16_rne(v - bf16_to_f(h));
    }
    unsigned short* dh = wgh + (size_t)gid*8;
    unsigned short* dl = wgl + (size_t)gid*8;
    #pragma unroll
    for (int j=0;j<8;++j) { dh[j] = hv[j]; dl[j] = lv[j]; }
}

// Fused conv1 (1x1, exact fp32) -> hi/lo NHWC bf16 [b][pix][64].
__global__ __launch_bounds__(256) void conv1_fused(
    const float* __restrict__ s, const float* __restrict__ l,
    const float* __restrict__ w, const float* __restrict__ bias,
    unsigned short* __restrict__ t0)
{
    int gid = blockIdx.x*256 + threadIdx.x;   // nb*HWSZ
    int b = gid >> 16;
    int pix = gid & (HWSZ-1);
    const float* sp = s + (size_t)b*CH*HWSZ + pix;
    const float* lp = l + (size_t)b*CH*HWSZ + pix;
    float acc[CH];
    #pragma unroll
    for (int o=0;o<CH;++o) acc[o] = bias[o];
    for (int c=0;c<CH;++c) {
        float v = sp[(size_t)c*HWSZ];
        #pragma unroll
        for (int o=0;o<CH;++o) acc[o] += w[o*64+c]*v;
    }
    for (int c=0;c<CH;++c) {
        float v = lp[(size_t)c*HWSZ];
        #pragma unroll
        for (int o=0;o<CH;++o) acc[o] += w[o*64+32+c]*v;
    }
    unsigned short* op = t0 + (size_t)gid*64;
    #pragma unroll
    for (int cb=0; cb<4; ++cb) {
        unsigned short hv[8], lv[8];
        #pragma unroll
        for (int j=0;j<8;++j) {
            float v = acc[cb*8+j];
            unsigned short h = bf16_rne(v);
            hv[j] = h;
            lv[j] = bf16_rne(v - bf16_to_f(h));
        }
        *reinterpret_cast<uint4*>(op + cb*8)      = *reinterpret_cast<uint4*>(hv);
        *reinterpret_cast<uint4*>(op + 32 + cb*8) = *reinterpret_cast<uint4*>(lv);
    }
}

__global__ __launch_bounds__(256) void up2_hl(
    const float* __restrict__ x, unsigned short* __restrict__ xq)
{
    int gid = blockIdx.x*256 + threadIdx.x;   // nb*HWSZ
    int b = gid >> 16;
    int pix = gid & (HWSZ-1);
    int oh = pix >> 8, ow = pix & 255;
    const int Hin = 128, Win = 128;
    float cy = (oh + 0.5f)*0.5f - 0.5f;
    float cx = (ow + 0.5f)*0.5f - 0.5f;
    cy = fminf(fmaxf(cy, 0.f), (float)(Hin-1));
    cx = fminf(fmaxf(cx, 0.f), (float)(Win-1));
    int y0 = (int)floorf(cy);
    int x0 = (int)floorf(cx);
    int y1 = min(y0+1, Hin-1);
    int x1 = min(x0+1, Win-1);
    float ty = cy - (float)y0, tx = cx - (float)x0;
    float w00 = (1.f-ty)*(1.f-tx), w01 = (1.f-ty)*tx;
    float w10 = ty*(1.f-tx),       w11 = ty*tx;
    unsigned short* op = xq + (size_t)gid*128;
    const float* xb = x + (size_t)b*32*Hin*Win;
    #pragma unroll
    for (int cb=0; cb<4; ++cb) {
        unsigned short hv[8], lv[8];
        #pragma unroll
        for (int j=0;j<8;++j) {
            const float* xp = xb + (size_t)(cb*8+j)*Hin*Win;
            float v = 2.0f*(xp[y0*Win+x0]*w00 + xp[y0*Win+x1]*w01 +
                            xp[y1*Win+x0]*w10 + xp[y1*Win+x1]*w11);
            unsigned short h = bf16_rne(v);
            hv[j] = h;
            lv[j] = bf16_rne(v - bf16_to_f(h));
        }
        *reinterpret_cast<uint4*>(op + 32 + cb*8)      = *reinterpret_cast<uint4*>(hv);
        *reinterpret_cast<uint4*>(op + 96 + cb*8)      = *reinterpret_cast<uint4*>(lv);
    }
}

// Cout=32 conv via MFMA with double-bf16 hi/lo.
// R23: the ks loop body is now BRANCH-FREE (clamped h + mask instead of
// `continue`) so `#pragma unroll 3` can actually pipeline loads across
// iterations. R23 counters showed the continue blocked pipelining: VGPR
// stayed 32, dur unchanged, effective BW 1.35 TB/s == the 8-wave x 4-load
// x 900-cyc HBM-latency bound. Straight-line body -> 12 loads in flight.
template<int TAPS, int F, bool RELU, bool NCHW_OUT, bool LO_OUT>
__global__ __launch_bounds__(256) void conv_mfma(
    const unsigned short* __restrict__ xq,
    const unsigned short* __restrict__ wphi,
    const unsigned short* __restrict__ wplo,
    const float* __restrict__ bias,
    unsigned short* __restrict__ yq, int ochs, int ohioff, int oloff,
    float* __restrict__ ynchw)
{
    int bid = blockIdx.x;               // nb*HH*4
    int wq = bid & 3;
    int h  = (bid >> 2) & 255;
    int b  = bid >> 10;
    int wv = threadIdx.x >> 6;
    int l  = threadIdx.x & 63;
    int w0 = wq*64 + wv*16;
    int lw = l & 15;
    int lq = l >> 4;
    const int CHS = 2*F*32;

    f32x4 acc[2];
    acc[0] = (f32x4){0.f,0.f,0.f,0.f};
    acc[1] = (f32x4){0.f,0.f,0.f,0.f};

    const unsigned short* xb = xq + (size_t)b*HWSZ*CHS;
    const bfrag zero = {0,0,0,0,0,0,0,0};

    #pragma unroll 3
    for (int ks=0; ks<TAPS; ++ks) {
        int dy = (TAPS==9) ? ks/3 - 1 : 0;
        int dx = (TAPS==9) ? ks%3 - 1 : 0;
        int hh = h + dy;
        bool vh = (hh >= 0) && (hh < HH);
        int hhc = min(max(hh, 0), HH-1);
        int wx = w0 + lw + dx;
        bool valid = vh && (wx >= 0) && (wx < WW);
        int wxc = min(max(wx, 0), WW-1);
        const unsigned short* xp = xb + ((size_t)hhc*WW + wxc)*CHS + lq*8;
        bfrag bh[F], bl[F];
        #pragma unroll
        for (int f=0;f<F;++f) {
            bh[f] = *reinterpret_cast<const bfrag*>(xp + f*32);
            bl[f] = *reinterpret_cast<const bfrag*>(xp + F*32 + f*32);
            bh[f] = valid ? bh[f] : zero;
            bl[f] = valid ? bl[f] : zero;
        }
        #pragma unroll
        for (int nt=0; nt<2; ++nt) {
            #pragma unroll
            for (int f=0;f<F;++f) {
                size_t widx = ((size_t)((ks*F + f)*2 + nt)*64 + l)*8;
                bfrag ah = *reinterpret_cast<const bfrag*>(wphi + widx);
                bfrag al = *reinterpret_cast<const bfrag*>(wplo + widx);
                acc[nt] = __builtin_amdgcn_mfma_f32_16x16x32_bf16(ah, bh[f], acc[nt], 0, 0, 0);
                acc[nt] = __builtin_amdgcn_mfma_f32_16x16x32_bf16(ah, bl[f], acc[nt], 0, 0, 0);
                acc[nt] = __builtin_amdgcn_mfma_f32_16x16x32_bf16(al, bh[f], acc[nt], 0, 0, 0);
            }
        }
    }

    int pw = w0 + lw;
    size_t pix = (size_t)h*WW + pw;
    #pragma unroll
    for (int nt=0; nt<2; ++nt) {
        float yv[4];
        #pragma unroll
        for (int i=0;i<4;++i) {
            int oc = nt*16 + lq*4 + i;
            float v = acc[nt][i] + bias[oc];
            yv[i] = RELU ? lrelu_f(v) : v;
        }
        unsigned short hv[4], lv[4];
        #pragma unroll
        for (int i=0;i<4;++i) {
            unsigned short hbits = bf16_rne(yv[i]);
            hv[i] = hbits;
            lv[i] = bf16_rne(yv[i] - bf16_to_f(hbits));
        }
        size_t obase = ((size_t)b*HWSZ + pix)*ochs + nt*16 + lq*4;
        *reinterpret_cast<ushort4*>(yq + obase + ohioff) = *reinterpret_cast<ushort4*>(hv);
        if (LO_OUT)
            *reinterpret_cast<ushort4*>(yq + obase + oloff) = *reinterpret_cast<ushort4*>(lv);
        if (NCHW_OUT) {
            #pragma unroll
            for (int i=0;i<4;++i) {
                int oc = nt*16 + lq*4 + i;
                ynchw[((size_t)(b*32 + oc))*HWSZ + pix] = yv[i];
            }
        }
    }
}

// 3x3 conv 32->216 via MFMA; om output bf16. ks loop stays ROLLED (acc[14]).
__global__ __launch_bounds__(256) void dcn_off_mfma(
    const unsigned short* __restrict__ xq,   // [nb,H,W,32] bf16 (hi)
    const unsigned short* __restrict__ wp,   // [9][14][64][8]
    const float* __restrict__ bias,
    unsigned short* __restrict__ om,         // [nb][216][HWSZ] bf16
    int r0, int rows)
{
    int bid = blockIdx.x;                    // nb*rows*4
    int wq = bid & 3;
    int rloc = (bid >> 2) % rows;
    int b  = (bid >> 2) / rows;
    int h  = r0 + rloc;
    int wv = threadIdx.x >> 6;
    int l  = threadIdx.x & 63;
    int w0 = wq*64 + wv*16;
    int lw = l & 15;
    int lq = l >> 4;

    f32x4 acc[14];
    #pragma unroll
    for (int t=0;t<14;++t) acc[t] = (f32x4){0.f,0.f,0.f,0.f};

    const unsigned short* xb = xq + (size_t)b*HWSZ*32;
    const bfrag zero = {0,0,0,0,0,0,0,0};

    #pragma unroll 1
    for (int ks=0; ks<9; ++ks) {
        int dy = ks/3 - 1, dx = ks%3 - 1;
        int hh = h + dy;
        if (hh < 0 || hh >= HH) continue;
        int wx = w0 + lw + dx;
        bool vw = (wx >= 0) && (wx < WW);
        int wxc = min(max(wx, 0), WW-1);
        const unsigned short* xp = xb + ((size_t)hh*WW + wxc)*32 + lq*8;
        bfrag bfr = *reinterpret_cast<const bfrag*>(xp);
        bfr = vw ? bfr : zero;
        const unsigned short* wks = wp + (size_t)ks*14*64*8;
        #pragma unroll
        for (int nt=0; nt<14; ++nt) {
            bfrag afr = *reinterpret_cast<const bfrag*>(wks + ((size_t)nt*64 + l)*8);
            acc[nt] = __builtin_amdgcn_mfma_f32_16x16x32_bf16(afr, bfr, acc[nt], 0, 0, 0);
        }
    }

    unsigned short* omb = om + (size_t)b*216*HWSZ;
    size_t pbase = (size_t)h*WW + w0 + lw;
    #pragma unroll
    for (int nt=0; nt<14; ++nt) {
        #pragma unroll
        for (int i=0;i<4;++i) {
            int oc = nt*16 + lq*4 + i;
            if (oc < 216)
                omb[(size_t)oc*HWSZ + pbase] = bf16_rne(acc[nt][i] + bias[oc]);
        }
    }
}

// Stage 1: DCNv2 sampling ONLY. k-slice x9 -> grid (rows, 9, nb).
__global__ __launch_bounds__(256) void dcn_sample(
    const float* __restrict__ x,              // long_fea [nb,32,H,W] fp32
    const unsigned short* __restrict__ om,    // [nb][216][HWSZ] bf16
    unsigned int* __restrict__ vhi,           // [nb][144][rows*WW]
    unsigned int* __restrict__ vlo,
    int r0, int rows)
{
    const int b = blockIdx.z;
    const int k = blockIdx.y;                 // 0..8
    int rr = blockIdx.x;
    int cw = threadIdx.x;
    int h = r0 + rr;
    const float* xb = x + (size_t)b*CH*HWSZ;
    const unsigned short* omb = om + (size_t)b*216*HWSZ;
    int ppos = h*WW + cw;                     // global pix (om)
    size_t rowsWW = (size_t)rows*WW;
    size_t lpix = (size_t)rr*WW + cw;         // local pix (val)
    unsigned int* vhb = vhi + (size_t)b*144*rowsWW;
    unsigned int* vlb = vlo + (size_t)b*144*rowsWW;

    for (int g=0; g<8; ++g) {
        const float* xg = xb + (size_t)g*4*HWSZ;
        int oc = g*9+k;
        float dy = bf16_to_f(omb[(size_t)oc*HWSZ + ppos]);
        float dx = bf16_to_f(omb[(size_t)(72+oc)*HWSZ + ppos]);
        float mm = bf16_to_f(omb[(size_t)(144+oc)*HWSZ + ppos]);
        mm = 1.f/(1.f + __expf(-mm));
        float py = dy + (float)(h + k/3 - 1);
        float px = dx + (float)(cw + k%3 - 1);
        float y0f = floorf(py), x0f = floorf(px);
        int yi = (int)y0f, xi = (int)x0f;
        float ty = py - y0f, tx = px - x0f;
        float w00 = (1.f-ty)*(1.f-tx), w01 = (1.f-ty)*tx;
        float w10 = ty*(1.f-tx),       w11 = ty*tx;
        int yc0 = min(max(yi,0),HH-1),   yc1 = min(max(yi+1,0),HH-1);
        int xc0 = min(max(xi,0),WW-1),   xc1 = min(max(xi+1,0),WW-1);
        bool vy0 = (yi>=0)&&(yi<HH),     vy1 = (yi+1>=0)&&(yi+1<HH);
        bool vx0 = (xi>=0)&&(xi<WW),     vx1 = (xi+1>=0)&&(xi+1<WW);
        float f00 = (vy0&&vx0)? w00*mm : 0.f;
        float f01 = (vy0&&vx1)? w01*mm : 0.f;
        float f10 = (vy1&&vx0)? w10*mm : 0.f;
        float f11 = (vy1&&vx1)? w11*mm : 0.f;
        int i00 = yc0*WW+xc0, i01 = yc0*WW+xc1;
        int i10 = yc1*WW+xc0, i11 = yc1*WW+xc1;
        float val[4];
        #pragma unroll
        for (int c=0;c<4;++c) {
            const float* xc = xg + (size_t)c*HWSZ;
            val[c] = xc[i00]*f00 + xc[i01]*f01 + xc[i10]*f10 + xc[i11]*f11;
        }
        unsigned short h0 = bf16_rne(val[0]);
        unsigned short h1 = bf16_rne(val[1]);
        unsigned short h2 = bf16_rne(val[2]);
        unsigned short h3 = bf16_rne(val[3]);
        unsigned short l0 = bf16_rne(val[0] - bf16_to_f(h0));
        unsigned short l1 = bf16_rne(val[1] - bf16_to_f(h1));
        unsigned short l2 = bf16_rne(val[2] - bf16_to_f(h2));
        unsigned short l3 = bf16_rne(val[3] - bf16_to_f(h3));
        size_t r0w = (size_t)(oc*2)*rowsWW + lpix;
        size_t r1w = (size_t)(oc*2+1)*rowsWW + lpix;
        vhb[r0w] = (unsigned)h0 | ((unsigned)h1 << 16);
        vhb[r1w] = (unsigned)h2 | ((unsigned)h3 << 16);
        vlb[r0w] = (unsigned)l0 | ((unsigned)l1 << 16);
        vlb[r1w] = (unsigned)l2 | ((unsigned)l3 << 16);
    }
}

// Stage 2: einsum as MFMA GEMM out[32, pix] = W[32,288] . val (hi/lo).
__global__ __launch_bounds__(256) void dcn_gemm(
    const unsigned int* __restrict__ vhi,    // [nb][144][rows*WW]
    const unsigned int* __restrict__ vlo,
    const unsigned short* __restrict__ wgh,  // [9][2][64][8]
    const unsigned short* __restrict__ wgl,
    const float* __restrict__ bias,
    float* __restrict__ y,                   // out [nb,32,H,W]
    int r0, int rows)
{
    int bid = blockIdx.x;                    // nb*rows*4
    int wq = bid & 3;
    int rloc = (bid >> 2) % rows;
    int b  = (bid >> 2) / rows;
    int h  = r0 + rloc;
    int wv = threadIdx.x >> 6;
    int l  = threadIdx.x & 63;
    int w0 = wq*64 + wv*16;
    int lw = l & 15;
    int lq = l >> 4;
    size_t rowsWW = (size_t)rows*WW;
    const unsigned int* vhb = vhi + (size_t)b*144*rowsWW;
    const unsigned int* vlb = vlo + (size_t)b*144*rowsWW;
    size_t p = (size_t)rloc*WW + w0 + lw;

    f32x4 acc[2];
    acc[0] = (f32x4){0.f,0.f,0.f,0.f};
    acc[1] = (f32x4){0.f,0.f,0.f,0.f};

    #pragma unroll 3
    for (int ks=0; ks<9; ++ks) {
        int urow = ks*16 + lq*4;
        __attribute__((aligned(16))) unsigned int uh[4], ul[4];
        #pragma unroll
        for (int j=0;j<4;++j) {
            uh[j] = vhb[(size_t)(urow+j)*rowsWW + p];
            ul[j] = vlb[(size_t)(urow+j)*rowsWW + p];
        }
        bfrag bh = *reinterpret_cast<const bfrag*>(uh);
        bfrag bl = *reinterpret_cast<const bfrag*>(ul);
        const unsigned short* wk_h = wgh + (size_t)ks*2*64*8;
        const unsigned short* wk_l = wgl + (size_t)ks*2*64*8;
        #pragma unroll
        for (int nt=0; nt<2; ++nt) {
            bfrag ah = *reinterpret_cast<const bfrag*>(wk_h + ((size_t)nt*64 + l)*8);
            bfrag al = *reinterpret_cast<const bfrag*>(wk_l + ((size_t)nt*64 + l)*8);
            acc[nt] = __builtin_amdgcn_mfma_f32_16x16x32_bf16(ah, bh, acc[nt], 0, 0, 0);
            acc[nt] = __builtin_amdgcn_mfma_f32_16x16x32_bf16(ah, bl, acc[nt], 0, 0, 0);
            acc[nt] = __builtin_amdgcn_mfma_f32_16x16x32_bf16(al, bh, acc[nt], 0, 0, 0);
        }
    }

    float* yb = y + (size_t)b*CH*HWSZ + (size_t)h*WW + w0 + lw;
    #pragma unroll
    for (int nt=0; nt<2; ++nt) {
        #pragma unroll
        for (int i=0;i<4;++i) {
            int oc = nt*16 + lq*4 + i;
            yb[(size_t)oc*HWSZ] = lrelu_f(acc[nt][i] + bias[oc]);
        }
    }
}

extern "C" void kernel_launch(void* const* d_in, const int* in_sizes, int n_in,
                              void* d_out, int out_size, void* d_ws, size_t ws_size,
                              hipStream_t stream)
{
    (void)in_sizes; (void)n_in; (void)out_size;
    const float* short_fea = (const float*)d_in[0];
    const float* long_fea  = (const float*)d_in[1];
    const float* prev      = (const float*)d_in[2];
    const float* conv1_w   = (const float*)d_in[3];
    const float* conv1_b   = (const float*)d_in[4];
    const float* oc1_w     = (const float*)d_in[5];
    const float* oc1_b     = (const float*)d_in[6];
    const float* oc2_w     = (const float*)d_in[7];
    const float* oc2_b     = (const float*)d_in[8];
    const float* oc3_w     = (const float*)d_in[9];
    const float* oc3_b     = (const float*)d_in[10];
    const float* dow       = (const float*)d_in[11];
    const float* dob       = (const float*)d_in[12];
    const float* dcw       = (const float*)d_in[13];
    const float* dcb       = (const float*)d_in[14];

    float* out = (float*)d_out;                       // [2,32,256,256]
    float* off_out = out + (size_t)2*CH*HWSZ;         // [2,32,256,256]

    const int CROWS = 128;                             // val row-chunk
    size_t om_b   = (size_t)2*216*HWSZ*2;              // 56.6 MB (bf16)
    size_t cat_b  = (size_t)2*HWSZ*128*2;              // 33.6 MB (overlaps om)
    size_t t_b    = (size_t)2*HWSZ*64*2;               // 16.8 MB (overlaps om)
    size_t xo_b   = (size_t)2*HWSZ*32*2;               // 8.4 MB
    size_t val_b  = (size_t)2*144*CROWS*WW*4;          // 37.75 MB per array
    size_t wpk_b  = (size_t)9*14*64*8*2;
    size_t wo1_b  = (size_t)9*1*2*64*8*2;
    size_t wo2_b  = (size_t)9*2*2*64*8*2;
    size_t wo3_b  = (size_t)9*1*2*64*8*2;
    size_t wg_b   = (size_t)9*2*64*8*2;
    size_t needed = om_b + xo_b + 2*val_b + wpk_b + 2*(wo1_b+wo2_b+wo3_b) + 2*wg_b;

    if (ws_size >= needed && om_b >= cat_b + t_b) {
        char* p = (char*)d_ws;
        unsigned short* om = (unsigned short*)p;
        unsigned short* cat  = (unsigned short*)p;                 // inside om
        unsigned short* tbuf = (unsigned short*)(p + cat_b);       // inside om
        p += om_b;
        unsigned short* xqo = (unsigned short*)p;  p += xo_b;
        unsigned int* vhi = (unsigned int*)p;      p += val_b;
        unsigned int* vlo = (unsigned int*)p;      p += val_b;
        unsigned short* wpk = (unsigned short*)p;  p += wpk_b;
        unsigned short* wo1h = (unsigned short*)p; p += wo1_b;
        unsigned short* wo1l = (unsigned short*)p; p += wo1_b;
        unsigned short* wo2h = (unsigned short*)p; p += wo2_b;
        unsigned short* wo2l = (unsigned short*)p; p += wo2_b;
        unsigned short* wo3h = (unsigned short*)p; p += wo3_b;
        unsigned short* wo3l = (unsigned short*)p; p += wo3_b;
        unsigned short* wgh = (unsigned short*)p;  p += wg_b;
        unsigned short* wgl = (unsigned short*)p;

        pack_conv_hl<<<5, 256, 0, stream>>>(oc1_w, wo1h, wo1l, 9, 1);
        pack_conv_hl<<<9, 256, 0, stream>>>(oc2_w, wo2h, wo2l, 9, 2);
        pack_conv_hl<<<5, 256, 0, stream>>>(oc3_w, wo3h, wo3l, 9, 1);
        pack_w_bf16<<<32, 256, 0, stream>>>(dow, wpk);
        pack_wg<<<5, 256, 0, stream>>>(dcw, wgh, wgl);

        const int PIX_BLOCKS = (2*HWSZ)/256;   // 512
        const int CONV_BLOCKS = 2*HH*4;        // 2048

        conv1_fused<<<PIX_BLOCKS, 256, 0, stream>>>(short_fea, long_fea, conv1_w, conv1_b, tbuf);
        conv_mfma<9,1,true,false,true><<<CONV_BLOCKS, 256, 0, stream>>>(
            tbuf, wo1h, wo1l, oc1_b, cat, 128, 0, 64, nullptr);
        up2_hl<<<PIX_BLOCKS, 256, 0, stream>>>(prev, cat);
        conv_mfma<9,2,true,false,true><<<CONV_BLOCKS, 256, 0, stream>>>(
            cat, wo2h, wo2l, oc2_b, tbuf, 64, 0, 32, nullptr);
        conv_mfma<9,1,true,true,false><<<CONV_BLOCKS, 256, 0, stream>>>(
            tbuf, wo3h, wo3l, oc3_b, xqo, 32, 0, 0, off_out);

        // cat/tbuf dead; om (bf16) may be written.
        dcn_off_mfma<<<2*HH*4, 256, 0, stream>>>(xqo, wpk, dob, om, 0, HH);

        for (int r0 = 0; r0 < HH; r0 += CROWS) {
            dim3 gs(CROWS, 9, 2);   // 2304 blocks -> 9216 waves
            dcn_sample<<<gs, 256, 0, stream>>>(long_fea, om, vhi, vlo, r0, CROWS);
            dcn_gemm<<<2*CROWS*4, 256, 0, stream>>>(vhi, vlo, wgh, wgl, dcb, out, r0, CROWS);
        }
    } else {
        // fp32 fallback
        float* bufB = (float*)d_ws;
        float* bufU = bufB + (size_t)2*CH*HWSZ;
        float* om   = bufU + (size_t)2*CH*HWSZ;
        size_t used = (size_t)2 * 2*CH*HWSZ * sizeof(float);
        size_t avail = (ws_size > used) ? (ws_size - used) : 0;
        const int PIX_BLOCKS = (2*HWSZ)/256;

        conv1x1_kernel<<<PIX_BLOCKS, 256, 0, stream>>>(short_fea, long_fea, conv1_w, conv1_b, out);
        conv3x3_kernel<1><<<PIX_BLOCKS, 256, 0, stream>>>(out, nullptr, oc1_w, oc1_b, bufB, 1);
        up2_kernel<<<(2*CH*HWSZ)/256, 256, 0, stream>>>(prev, bufU);
        conv3x3_kernel<2><<<PIX_BLOCKS, 256, 0, stream>>>(bufB, bufU, oc2_w, oc2_b, out, 1);
        conv3x3_kernel<1><<<PIX_BLOCKS, 256, 0, stream>>>(out, nullptr, oc3_w, oc3_b, off_out, 1);

        size_t per_row = (size_t)216 * WW * sizeof(float);
        int rows_chunk = (int)(avail / per_row);
        if (rows_chunk < 1) rows_chunk = 1;
        if (rows_chunk > HH) rows_chunk = HH;
        for (int b=0;b<2;++b) {
            const float* offb = off_out + (size_t)b*CH*HWSZ;
            const float* lfb  = long_fea + (size_t)b*CH*HWSZ;
            float* outb = out + (size_t)b*CH*HWSZ;
            for (int r0=0;r0<HH;r0+=rows_chunk) {
                int rows = (HH - r0 < rows_chunk) ? (HH - r0) : rows_chunk;
                dim3 g1(rows, 9);
                dcn_off_kernel<<<g1, 256, 0, stream>>>(offb, dow, dob, om, r0, rows);
                dim3 g2f(rows, 2, 1);
                dcn_kernel<<<g2f, 256, 0, stream>>>(lfb, om, dcw, dcb, outb, r0, rows);
            }
        }
    }
}

// Round 25
// 321.702 us; speedup vs baseline: 1.0833x; 1.0833x over previous
//
#include <hip/hip_runtime.h>

#define HH 256
#define WW 256
#define HWSZ (HH*WW)
#define CH 32

typedef __attribute__((ext_vector_type(8))) short bfrag;   // 8 bf16 = 4 VGPRs
typedef __attribute__((ext_vector_type(4))) float f32x4;

__device__ __forceinline__ float lrelu_f(float x){ return x >= 0.f ? x : 0.2f*x; }

__device__ __forceinline__ unsigned short bf16_rne(float f){
    unsigned int u = __float_as_uint(f);
    unsigned int r = (u + 0x7fffu + ((u >> 16) & 1u)) >> 16;
    return (unsigned short)r;
}
__device__ __forceinline__ float bf16_to_f(unsigned short h){
    return __uint_as_float(((unsigned int)h) << 16);
}

// ============================ fp32 fallback kernels =========================

__global__ __launch_bounds__(256) void conv1x1_kernel(
    const float* __restrict__ s, const float* __restrict__ l,
    const float* __restrict__ w, const float* __restrict__ bias,
    float* __restrict__ y)
{
    int gid = blockIdx.x*256 + threadIdx.x;
    int b = gid >> 16;
    int pix = gid & (HWSZ-1);
    const float* sp = s + (size_t)b*CH*HWSZ + pix;
    const float* lp = l + (size_t)b*CH*HWSZ + pix;
    float acc[CH];
    #pragma unroll
    for (int o=0;o<CH;++o) acc[o] = bias[o];
    for (int c=0;c<CH;++c) {
        float v = sp[(size_t)c*HWSZ];
        #pragma unroll
        for (int o=0;o<CH;++o) acc[o] += w[o*64+c]*v;
    }
    for (int c=0;c<CH;++c) {
        float v = lp[(size_t)c*HWSZ];
        #pragma unroll
        for (int o=0;o<CH;++o) acc[o] += w[o*64+32+c]*v;
    }
    float* yp = y + (size_t)b*CH*HWSZ + pix;
    #pragma unroll
    for (int o=0;o<CH;++o) yp[(size_t)o*HWSZ] = acc[o];
}

template<int NP>
__global__ __launch_bounds__(256) void conv3x3_kernel(
    const float* __restrict__ x0, const float* __restrict__ x1,
    const float* __restrict__ w, const float* __restrict__ bias,
    float* __restrict__ y, int relu)
{
    int gid = blockIdx.x*256 + threadIdx.x;
    int b = gid >> 16;
    int pix = gid & (HWSZ-1);
    int h = pix >> 8, cw = pix & 255;
    const int CIN = 32*NP;
    float acc[CH];
    #pragma unroll
    for (int o=0;o<CH;++o) acc[o] = bias[o];
    #pragma unroll
    for (int p=0;p<NP;++p) {
        const float* src = (p==0) ? x0 : x1;
        const float* xb = src + (size_t)b*CH*HWSZ;
        for (int c=0;c<CH;++c) {
            const float* xp = xb + (size_t)c*HWSZ;
            float v[9];
            #pragma unroll
            for (int t=0;t<9;++t) {
                int hh = h + t/3 - 1;
                int wx = cw + t%3 - 1;
                v[t] = (hh>=0 && hh<HH && wx>=0 && wx<WW) ? xp[hh*WW+wx] : 0.f;
            }
            const float* wp = w + (size_t)(p*32 + c)*9;
            #pragma unroll
            for (int o=0;o<CH;++o) {
                #pragma unroll
                for (int t=0;t<9;++t)
                    acc[o] += wp[(size_t)o*CIN*9 + t] * v[t];
            }
        }
    }
    float* yp = y + (size_t)b*CH*HWSZ + pix;
    #pragma unroll
    for (int o=0;o<CH;++o)
        yp[(size_t)o*HWSZ] = relu ? lrelu_f(acc[o]) : acc[o];
}

__global__ __launch_bounds__(256) void up2_kernel(
    const float* __restrict__ x, float* __restrict__ y)
{
    int gid = blockIdx.x*256 + threadIdx.x;
    int ow = gid & 255;
    int oh = (gid >> 8) & 255;
    int bc = gid >> 16;
    const int Hin = 128, Win = 128;
    float cy = (oh + 0.5f)*0.5f - 0.5f;
    float cx = (ow + 0.5f)*0.5f - 0.5f;
    cy = fminf(fmaxf(cy, 0.f), (float)(Hin-1));
    cx = fminf(fmaxf(cx, 0.f), (float)(Win-1));
    int y0 = (int)floorf(cy);
    int x0 = (int)floorf(cx);
    int y1 = min(y0+1, Hin-1);
    int x1 = min(x0+1, Win-1);
    float ty = cy - (float)y0, tx = cx - (float)x0;
    const float* xp = x + (size_t)bc*Hin*Win;
    float v00 = xp[y0*Win+x0], v01 = xp[y0*Win+x1];
    float v10 = xp[y1*Win+x0], v11 = xp[y1*Win+x1];
    float v = v00*(1.f-ty)*(1.f-tx) + v01*(1.f-ty)*tx + v10*ty*(1.f-tx) + v11*ty*tx;
    y[gid] = 2.0f*v;
}

__global__ __launch_bounds__(256) void dcn_off_kernel(
    const float* __restrict__ x, const float* __restrict__ w,
    const float* __restrict__ bias, float* __restrict__ om,
    int r0, int rows)
{
    int b = blockIdx.x / rows;
    int rr = blockIdx.x % rows;
    int cw = threadIdx.x;
    int h = r0 + rr;
    int oc0 = blockIdx.y*24;
    const float* xb = x + (size_t)b*CH*HWSZ;
    float* omb = om + (size_t)b*216*rows*WW;
    float acc[24];
    #pragma unroll
    for (int j=0;j<24;++j) acc[j] = bias[oc0+j];
    for (int c=0;c<32;++c) {
        const float* xp = xb + (size_t)c*HWSZ;
        float v[9];
        #pragma unroll
        for (int t=0;t<9;++t) {
            int hh = h + t/3 - 1;
            int wx = cw + t%3 - 1;
            v[t] = (hh>=0 && hh<HH && wx>=0 && wx<WW) ? xp[hh*WW+wx] : 0.f;
        }
        const float* wpp = w + (size_t)c*9;
        #pragma unroll
        for (int j=0;j<24;++j) {
            #pragma unroll
            for (int t=0;t<9;++t)
                acc[j] += wpp[(size_t)(oc0+j)*288 + t] * v[t];
        }
    }
    #pragma unroll
    for (int j=0;j<24;++j)
        omb[(size_t)(oc0+j)*rows*WW + (size_t)rr*WW + cw] = acc[j];
}

// Legacy full sampling+einsum kernel (fallback path).
__global__ __launch_bounds__(256) void dcn_kernel(
    const float* __restrict__ x, const float* __restrict__ om,
    const float* __restrict__ w, const float* __restrict__ bias,
    float* __restrict__ y, int r0, int rows)
{
    const int b  = blockIdx.z;
    const int os = blockIdx.y;
    const int rowsWW = rows*WW;
    int rr = blockIdx.x;
    int cw = threadIdx.x;
    int h = r0 + rr;
    const float* xb  = x  + (size_t)b*CH*HWSZ;
    const float* omb = om + (size_t)b*216*rowsWW;
    int ppos = rr*WW + cw;
    int ob = os*16;

    float acc[16];
    #pragma unroll
    for (int o=0;o<16;++o) acc[o] = bias[ob+o];

    for (int g=0; g<8; ++g) {
        const float* xg = xb + (size_t)g*4*HWSZ;
        #pragma unroll
        for (int k=0;k<9;++k) {
            int oc = g*9+k;
            float dy = omb[(size_t)oc*rowsWW + ppos];
            float dx = omb[(size_t)(72+oc)*rowsWW + ppos];
            float mm = omb[(size_t)(144+oc)*rowsWW + ppos];
            mm = 1.f/(1.f + __expf(-mm));
            float py = dy + (float)(h + k/3 - 1);
            float px = dx + (float)(cw + k%3 - 1);
            float y0f = floorf(py), x0f = floorf(px);
            int yi = (int)y0f, xi = (int)x0f;
            float ty = py - y0f, tx = px - x0f;
            float w00 = (1.f-ty)*(1.f-tx), w01 = (1.f-ty)*tx;
            float w10 = ty*(1.f-tx),       w11 = ty*tx;
            int yc0 = min(max(yi,0),HH-1),   yc1 = min(max(yi+1,0),HH-1);
            int xc0 = min(max(xi,0),WW-1),   xc1 = min(max(xi+1,0),WW-1);
            bool vy0 = (yi>=0)&&(yi<HH),     vy1 = (yi+1>=0)&&(yi+1<HH);
            bool vx0 = (xi>=0)&&(xi<WW),     vx1 = (xi+1>=0)&&(xi+1<WW);
            float f00 = (vy0&&vx0)? w00*mm : 0.f;
            float f01 = (vy0&&vx1)? w01*mm : 0.f;
            float f10 = (vy1&&vx0)? w10*mm : 0.f;
            float f11 = (vy1&&vx1)? w11*mm : 0.f;
            int i00 = yc0*WW+xc0, i01 = yc0*WW+xc1;
            int i10 = yc1*WW+xc0, i11 = yc1*WW+xc1;
            #pragma unroll
            for (int c=0;c<4;++c) {
                const float* xc = xg + (size_t)c*HWSZ;
                float val = xc[i00]*f00 + xc[i01]*f01 + xc[i10]*f10 + xc[i11]*f11;
                const float* wpp = w + (size_t)(g*4+c)*9 + k;
                #pragma unroll
                for (int o=0;o<16;++o)
                    acc[o] += wpp[(size_t)(ob+o)*288] * val;
            }
        }
    }

    float* yb = y + (size_t)(b*CH + ob)*HWSZ + (size_t)h*WW;
    #pragma unroll
    for (int o=0;o<16;++o)
        yb[(size_t)o*HWSZ + cw] = lrelu_f(acc[o]);
}

// ============================ bf16 MFMA path ================================

__global__ __launch_bounds__(256) void pack_w_bf16(
    const float* __restrict__ dow, unsigned short* __restrict__ wp)
{
    int gid = blockIdx.x*256 + threadIdx.x;   // 9*14*64
    if (gid >= 9*14*64) return;
    int l = gid & 63;
    int rest = gid >> 6;
    int nt = rest % 14;
    int ks = rest / 14;
    int oc = nt*16 + (l & 15);
    int c0 = 8*(l >> 4);
    unsigned short outv[8];
    #pragma unroll
    for (int j=0;j<8;++j) {
        float v = (oc < 216) ? dow[(size_t)oc*288 + (size_t)(c0+j)*9 + ks] : 0.f;
        outv[j] = bf16_rne(v);
    }
    unsigned short* dst = wp + (size_t)gid*8;
    #pragma unroll
    for (int j=0;j<8;++j) dst[j] = outv[j];
}

__global__ __launch_bounds__(256) void pack_conv_hl(
    const float* __restrict__ w, unsigned short* __restrict__ wphi,
    unsigned short* __restrict__ wplo, int TAPS, int F)
{
    int total = TAPS*F*2*64;
    int gid = blockIdx.x*256 + threadIdx.x;
    if (gid >= total) return;
    int l = gid & 63;
    int q = gid >> 6;
    int nt = q & 1;
    int p = q >> 1;
    int f = p % F;
    int ks = p / F;
    int oc = nt*16 + (l & 15);
    int CIN = F*32;
    unsigned short hv[8], lv[8];
    #pragma unroll
    for (int j=0;j<8;++j) {
        int c = f*32 + (l>>4)*8 + j;
        float v = w[(size_t)oc*CIN*TAPS + (size_t)c*TAPS + ks];
        unsigned short h = bf16_rne(v);
        hv[j] = h;
        lv[j] = bf16_rne(v - bf16_to_f(h));
    }
    unsigned short* dh = wphi + (size_t)gid*8;
    unsigned short* dl = wplo + (size_t)gid*8;
    #pragma unroll
    for (int j=0;j<8;++j) { dh[j] = hv[j]; dl[j] = lv[j]; }
}

// Pack dcn einsum weights for the val-GEMM: K = (g*9+k)*4 + c, hi/lo.
__global__ __launch_bounds__(256) void pack_wg(
    const float* __restrict__ dcw, unsigned short* __restrict__ wgh,
    unsigned short* __restrict__ wgl)
{
    int gid = blockIdx.x*256 + threadIdx.x;   // 9*2*64 = 1152
    if (gid >= 1152) return;
    int l = gid & 63;
    int q = gid >> 6;
    int nt = q & 1;
    int ks = q >> 1;
    int oc = nt*16 + (l & 15);
    unsigned short hv[8], lv[8];
    #pragma unroll
    for (int j=0;j<8;++j) {
        int K = ks*32 + (l>>4)*8 + j;
        int g = K/36;
        int rem = K - g*36;
        int kk = rem >> 2;
        int c = rem & 3;
        float v = dcw[(size_t)oc*288 + (size_t)(g*4+c)*9 + kk];
        unsigned short h = bf16_rne(v);
        hv[j] = h;
        lv[j] = bf16_rne(v - bf16_to_f(h));
    }
    unsigned short* dh = wgh + (size_t)gid*8;
    unsigned short* dl = wgl + (size_t)gid*8;
    #pragma unroll
    for (int j=0;j<8;++j) { dh[j] = hv[j]; dl[j] = lv[j]; }
}

// Fused conv1 (1x1, exact fp32) -> hi/lo NHWC bf16 [b][pix][64].
__global__ __launch_bounds__(256) void conv1_fused(
    const float* __restrict__ s, const float* __restrict__ l,
    const float* __restrict__ w, const float* __restrict__ bias,
    unsigned short* __restrict__ t0)
{
    int gid = blockIdx.x*256 + threadIdx.x;   // nb*HWSZ
    int b = gid >> 16;
    int pix = gid & (HWSZ-1);
    const float* sp = s + (size_t)b*CH*HWSZ + pix;
    const float* lp = l + (size_t)b*CH*HWSZ + pix;
    float acc[CH];
    #pragma unroll
    for (int o=0;o<CH;++o) acc[o] = bias[o];
    for (int c=0;c<CH;++c) {
        float v = sp[(size_t)c*HWSZ];
        #pragma unroll
        for (int o=0;o<CH;++o) acc[o] += w[o*64+c]*v;
    }
    for (int c=0;c<CH;++c) {
        float v = lp[(size_t)c*HWSZ];
        #pragma unroll
        for (int o=0;o<CH;++o) acc[o] += w[o*64+32+c]*v;
    }
    unsigned short* op = t0 + (size_t)gid*64;
    #pragma unroll
    for (int cb=0; cb<4; ++cb) {
        unsigned short hv[8], lv[8];
        #pragma unroll
        for (int j=0;j<8;++j) {
            float v = acc[cb*8+j];
            unsigned short h = bf16_rne(v);
            hv[j] = h;
            lv[j] = bf16_rne(v - bf16_to_f(h));
        }
        *reinterpret_cast<uint4*>(op + cb*8)      = *reinterpret_cast<uint4*>(hv);
        *reinterpret_cast<uint4*>(op + 32 + cb*8) = *reinterpret_cast<uint4*>(lv);
    }
}

__global__ __launch_bounds__(256) void up2_hl(
    const float* __restrict__ x, unsigned short* __restrict__ xq)
{
    int gid = blockIdx.x*256 + threadIdx.x;   // nb*HWSZ
    int b = gid >> 16;
    int pix = gid & (HWSZ-1);
    int oh = pix >> 8, ow = pix & 255;
    const int Hin = 128, Win = 128;
    float cy = (oh + 0.5f)*0.5f - 0.5f;
    float cx = (ow + 0.5f)*0.5f - 0.5f;
    cy = fminf(fmaxf(cy, 0.f), (float)(Hin-1));
    cx = fminf(fmaxf(cx, 0.f), (float)(Win-1));
    int y0 = (int)floorf(cy);
    int x0 = (int)floorf(cx);
    int y1 = min(y0+1, Hin-1);
    int x1 = min(x0+1, Win-1);
    float ty = cy - (float)y0, tx = cx - (float)x0;
    float w00 = (1.f-ty)*(1.f-tx), w01 = (1.f-ty)*tx;
    float w10 = ty*(1.f-tx),       w11 = ty*tx;
    unsigned short* op = xq + (size_t)gid*128;
    const float* xb = x + (size_t)b*32*Hin*Win;
    #pragma unroll
    for (int cb=0; cb<4; ++cb) {
        unsigned short hv[8], lv[8];
        #pragma unroll
        for (int j=0;j<8;++j) {
            const float* xp = xb + (size_t)(cb*8+j)*Hin*Win;
            float v = 2.0f*(xp[y0*Win+x0]*w00 + xp[y0*Win+x1]*w01 +
                            xp[y1*Win+x0]*w10 + xp[y1*Win+x1]*w11);
            unsigned short h = bf16_rne(v);
            hv[j] = h;
            lv[j] = bf16_rne(v - bf16_to_f(h));
        }
        *reinterpret_cast<uint4*>(op + 32 + cb*8)      = *reinterpret_cast<uint4*>(hv);
        *reinterpret_cast<uint4*>(op + 96 + cb*8)      = *reinterpret_cast<uint4*>(lv);
    }
}

// Cout=32 conv via MFMA with double-bf16 hi/lo.
// R24: LDS-STAGED input tile. Two rounds of unroll attempts were nulls
// (compiler won't pipeline the global load->MFMA chain; VGPR stuck at 32,
// 1.3 TB/s latency-bound on 9x redundant tap re-reads). Now each block
// stages its 3-row x 66-px halo ONCE (independent, pipelined loads, zero-
// filled boundary) and serves all 18 fragment reads/thread from LDS.
// Record stride padded +8 shorts to break the 128/256B-stride bank conflict.
template<int TAPS, int F, bool RELU, bool NCHW_OUT, bool LO_OUT>
__global__ __launch_bounds__(256) void conv_mfma(
    const unsigned short* __restrict__ xq,
    const unsigned short* __restrict__ wphi,
    const unsigned short* __restrict__ wplo,
    const float* __restrict__ bias,
    unsigned short* __restrict__ yq, int ochs, int ohioff, int oloff,
    float* __restrict__ ynchw)
{
    constexpr int CHS = 2*F*32;          // shorts per pixel record
    constexpr int REC = CHS + 8;         // padded LDS record stride (shorts)
    __shared__ unsigned short lds[3*66*REC];

    int bid = blockIdx.x;               // nb*HH*4
    int wq = bid & 3;
    int h  = (bid >> 2) & 255;
    int b  = bid >> 10;
    int wv = threadIdx.x >> 6;
    int l  = threadIdx.x & 63;
    int blk_w0 = wq*64;
    int lw = l & 15;
    int lq = l >> 4;

    const unsigned short* xb = xq + (size_t)b*HWSZ*CHS;

    // ---- stage 3 rows x 66 px (zero-filled halo) ----
    constexpr int CH8 = CHS/8;           // 16B chunks per record
    constexpr int TOT = 3*66*CH8;
    for (int idx = threadIdx.x; idx < TOT; idx += 256) {
        int rec = idx / CH8;
        int off = (idx - rec*CH8)*8;
        int row = rec / 66;
        int j   = rec - row*66;
        int hh = h - 1 + row;
        int wx = blk_w0 - 1 + j;
        uint4 v = {0u,0u,0u,0u};
        if (hh >= 0 && hh < HH && wx >= 0 && wx < WW)
            v = *reinterpret_cast<const uint4*>(xb + ((size_t)hh*WW + wx)*CHS + off);
        *reinterpret_cast<uint4*>(&lds[(size_t)rec*REC + off]) = v;
    }
    __syncthreads();

    f32x4 acc[2];
    acc[0] = (f32x4){0.f,0.f,0.f,0.f};
    acc[1] = (f32x4){0.f,0.f,0.f,0.f};

    int jbase = wv*16 + lw;              // pixel offset within block (0..63)

    #pragma unroll 3
    for (int ks=0; ks<TAPS; ++ks) {
        int row  = (TAPS==9) ? ks/3 : 1;
        int dxp1 = (TAPS==9) ? ks%3 : 1;
        int rec = row*66 + jbase + dxp1;
        const unsigned short* xp = &lds[(size_t)rec*REC + lq*8];
        bfrag bh[F], bl[F];
        #pragma unroll
        for (int f=0;f<F;++f) {
            bh[f] = *reinterpret_cast<const bfrag*>(xp + f*32);
            bl[f] = *reinterpret_cast<const bfrag*>(xp + F*32 + f*32);
        }
        #pragma unroll
        for (int nt=0; nt<2; ++nt) {
            #pragma unroll
            for (int f=0;f<F;++f) {
                size_t widx = ((size_t)((ks*F + f)*2 + nt)*64 + l)*8;
                bfrag ah = *reinterpret_cast<const bfrag*>(wphi + widx);
                bfrag al = *reinterpret_cast<const bfrag*>(wplo + widx);
                acc[nt] = __builtin_amdgcn_mfma_f32_16x16x32_bf16(ah, bh[f], acc[nt], 0, 0, 0);
                acc[nt] = __builtin_amdgcn_mfma_f32_16x16x32_bf16(ah, bl[f], acc[nt], 0, 0, 0);
                acc[nt] = __builtin_amdgcn_mfma_f32_16x16x32_bf16(al, bh[f], acc[nt], 0, 0, 0);
            }
        }
    }

    int pw = blk_w0 + jbase;
    size_t pix = (size_t)h*WW + pw;
    #pragma unroll
    for (int nt=0; nt<2; ++nt) {
        float yv[4];
        #pragma unroll
        for (int i=0;i<4;++i) {
            int oc = nt*16 + lq*4 + i;
            float v = acc[nt][i] + bias[oc];
            yv[i] = RELU ? lrelu_f(v) : v;
        }
        unsigned short hv[4], lv[4];
        #pragma unroll
        for (int i=0;i<4;++i) {
            unsigned short hbits = bf16_rne(yv[i]);
            hv[i] = hbits;
            lv[i] = bf16_rne(yv[i] - bf16_to_f(hbits));
        }
        size_t obase = ((size_t)b*HWSZ + pix)*ochs + nt*16 + lq*4;
        *reinterpret_cast<ushort4*>(yq + obase + ohioff) = *reinterpret_cast<ushort4*>(hv);
        if (LO_OUT)
            *reinterpret_cast<ushort4*>(yq + obase + oloff) = *reinterpret_cast<ushort4*>(lv);
        if (NCHW_OUT) {
            #pragma unroll
            for (int i=0;i<4;++i) {
                int oc = nt*16 + lq*4 + i;
                ynchw[((size_t)(b*32 + oc))*HWSZ + pix] = yv[i];
            }
        }
    }
}

// 3x3 conv 32->216 via MFMA; om output bf16. ks loop stays ROLLED (acc[14]).
__global__ __launch_bounds__(256) void dcn_off_mfma(
    const unsigned short* __restrict__ xq,   // [nb,H,W,32] bf16 (hi)
    const unsigned short* __restrict__ wp,   // [9][14][64][8]
    const float* __restrict__ bias,
    unsigned short* __restrict__ om,         // [nb][216][HWSZ] bf16
    int r0, int rows)
{
    int bid = blockIdx.x;                    // nb*rows*4
    int wq = bid & 3;
    int rloc = (bid >> 2) % rows;
    int b  = (bid >> 2) / rows;
    int h  = r0 + rloc;
    int wv = threadIdx.x >> 6;
    int l  = threadIdx.x & 63;
    int w0 = wq*64 + wv*16;
    int lw = l & 15;
    int lq = l >> 4;

    f32x4 acc[14];
    #pragma unroll
    for (int t=0;t<14;++t) acc[t] = (f32x4){0.f,0.f,0.f,0.f};

    const unsigned short* xb = xq + (size_t)b*HWSZ*32;
    const bfrag zero = {0,0,0,0,0,0,0,0};

    #pragma unroll 1
    for (int ks=0; ks<9; ++ks) {
        int dy = ks/3 - 1, dx = ks%3 - 1;
        int hh = h + dy;
        if (hh < 0 || hh >= HH) continue;
        int wx = w0 + lw + dx;
        bool vw = (wx >= 0) && (wx < WW);
        int wxc = min(max(wx, 0), WW-1);
        const unsigned short* xp = xb + ((size_t)hh*WW + wxc)*32 + lq*8;
        bfrag bfr = *reinterpret_cast<const bfrag*>(xp);
        bfr = vw ? bfr : zero;
        const unsigned short* wks = wp + (size_t)ks*14*64*8;
        #pragma unroll
        for (int nt=0; nt<14; ++nt) {
            bfrag afr = *reinterpret_cast<const bfrag*>(wks + ((size_t)nt*64 + l)*8);
            acc[nt] = __builtin_amdgcn_mfma_f32_16x16x32_bf16(afr, bfr, acc[nt], 0, 0, 0);
        }
    }

    unsigned short* omb = om + (size_t)b*216*HWSZ;
    size_t pbase = (size_t)h*WW + w0 + lw;
    #pragma unroll
    for (int nt=0; nt<14; ++nt) {
        #pragma unroll
        for (int i=0;i<4;++i) {
            int oc = nt*16 + lq*4 + i;
            if (oc < 216)
                omb[(size_t)oc*HWSZ + pbase] = bf16_rne(acc[nt][i] + bias[oc]);
        }
    }
}

// Stage 1: DCNv2 sampling ONLY. k-slice x9 -> grid (rows, 9, nb).
__global__ __launch_bounds__(256) void dcn_sample(
    const float* __restrict__ x,              // long_fea [nb,32,H,W] fp32
    const unsigned short* __restrict__ om,    // [nb][216][HWSZ] bf16
    unsigned int* __restrict__ vhi,           // [nb][144][rows*WW]
    unsigned int* __restrict__ vlo,
    int r0, int rows)
{
    const int b = blockIdx.z;
    const int k = blockIdx.y;                 // 0..8
    int rr = blockIdx.x;
    int cw = threadIdx.x;
    int h = r0 + rr;
    const float* xb = x + (size_t)b*CH*HWSZ;
    const unsigned short* omb = om + (size_t)b*216*HWSZ;
    int ppos = h*WW + cw;                     // global pix (om)
    size_t rowsWW = (size_t)rows*WW;
    size_t lpix = (size_t)rr*WW + cw;         // local pix (val)
    unsigned int* vhb = vhi + (size_t)b*144*rowsWW;
    unsigned int* vlb = vlo + (size_t)b*144*rowsWW;

    for (int g=0; g<8; ++g) {
        const float* xg = xb + (size_t)g*4*HWSZ;
        int oc = g*9+k;
        float dy = bf16_to_f(omb[(size_t)oc*HWSZ + ppos]);
        float dx = bf16_to_f(omb[(size_t)(72+oc)*HWSZ + ppos]);
        float mm = bf16_to_f(omb[(size_t)(144+oc)*HWSZ + ppos]);
        mm = 1.f/(1.f + __expf(-mm));
        float py = dy + (float)(h + k/3 - 1);
        float px = dx + (float)(cw + k%3 - 1);
        float y0f = floorf(py), x0f = floorf(px);
        int yi = (int)y0f, xi = (int)x0f;
        float ty = py - y0f, tx = px - x0f;
        float w00 = (1.f-ty)*(1.f-tx), w01 = (1.f-ty)*tx;
        float w10 = ty*(1.f-tx),       w11 = ty*tx;
        int yc0 = min(max(yi,0),HH-1),   yc1 = min(max(yi+1,0),HH-1);
        int xc0 = min(max(xi,0),WW-1),   xc1 = min(max(xi+1,0),WW-1);
        bool vy0 = (yi>=0)&&(yi<HH),     vy1 = (yi+1>=0)&&(yi+1<HH);
        bool vx0 = (xi>=0)&&(xi<WW),     vx1 = (xi+1>=0)&&(xi+1<WW);
        float f00 = (vy0&&vx0)? w00*mm : 0.f;
        float f01 = (vy0&&vx1)? w01*mm : 0.f;
        float f10 = (vy1&&vx0)? w10*mm : 0.f;
        float f11 = (vy1&&vx1)? w11*mm : 0.f;
        int i00 = yc0*WW+xc0, i01 = yc0*WW+xc1;
        int i10 = yc1*WW+xc0, i11 = yc1*WW+xc1;
        float val[4];
        #pragma unroll
        for (int c=0;c<4;++c) {
            const float* xc = xg + (size_t)c*HWSZ;
            val[c] = xc[i00]*f00 + xc[i01]*f01 + xc[i10]*f10 + xc[i11]*f11;
        }
        unsigned short h0 = bf16_rne(val[0]);
        unsigned short h1 = bf16_rne(val[1]);
        unsigned short h2 = bf16_rne(val[2]);
        unsigned short h3 = bf16_rne(val[3]);
        unsigned short l0 = bf16_rne(val[0] - bf16_to_f(h0));
        unsigned short l1 = bf16_rne(val[1] - bf16_to_f(h1));
        unsigned short l2 = bf16_rne(val[2] - bf16_to_f(h2));
        unsigned short l3 = bf16_rne(val[3] - bf16_to_f(h3));
        size_t r0w = (size_t)(oc*2)*rowsWW + lpix;
        size_t r1w = (size_t)(oc*2+1)*rowsWW + lpix;
        vhb[r0w] = (unsigned)h0 | ((unsigned)h1 << 16);
        vhb[r1w] = (unsigned)h2 | ((unsigned)h3 << 16);
        vlb[r0w] = (unsigned)l0 | ((unsigned)l1 << 16);
        vlb[r1w] = (unsigned)l2 | ((unsigned)l3 << 16);
    }
}

// Stage 2: einsum as MFMA GEMM out[32, pix] = W[32,288] . val (hi/lo).
__global__ __launch_bounds__(256) void dcn_gemm(
    const unsigned int* __restrict__ vhi,    // [nb][144][rows*WW]
    const unsigned int* __restrict__ vlo,
    const unsigned short* __restrict__ wgh,  // [9][2][64][8]
    const unsigned short* __restrict__ wgl,
    const float* __restrict__ bias,
    float* __restrict__ y,                   // out [nb,32,H,W]
    int r0, int rows)
{
    int bid = blockIdx.x;                    // nb*rows*4
    int wq = bid & 3;
    int rloc = (bid >> 2) % rows;
    int b  = (bid >> 2) / rows;
    int h  = r0 + rloc;
    int wv = threadIdx.x >> 6;
    int l  = threadIdx.x & 63;
    int w0 = wq*64 + wv*16;
    int lw = l & 15;
    int lq = l >> 4;
    size_t rowsWW = (size_t)rows*WW;
    const unsigned int* vhb = vhi + (size_t)b*144*rowsWW;
    const unsigned int* vlb = vlo + (size_t)b*144*rowsWW;
    size_t p = (size_t)rloc*WW + w0 + lw;

    f32x4 acc[2];
    acc[0] = (f32x4){0.f,0.f,0.f,0.f};
    acc[1] = (f32x4){0.f,0.f,0.f,0.f};

    #pragma unroll 3
    for (int ks=0; ks<9; ++ks) {
        int urow = ks*16 + lq*4;
        __attribute__((aligned(16))) unsigned int uh[4], ul[4];
        #pragma unroll
        for (int j=0;j<4;++j) {
            uh[j] = vhb[(size_t)(urow+j)*rowsWW + p];
            ul[j] = vlb[(size_t)(urow+j)*rowsWW + p];
        }
        bfrag bh = *reinterpret_cast<const bfrag*>(uh);
        bfrag bl = *reinterpret_cast<const bfrag*>(ul);
        const unsigned short* wk_h = wgh + (size_t)ks*2*64*8;
        const unsigned short* wk_l = wgl + (size_t)ks*2*64*8;
        #pragma unroll
        for (int nt=0; nt<2; ++nt) {
            bfrag ah = *reinterpret_cast<const bfrag*>(wk_h + ((size_t)nt*64 + l)*8);
            bfrag al = *reinterpret_cast<const bfrag*>(wk_l + ((size_t)nt*64 + l)*8);
            acc[nt] = __builtin_amdgcn_mfma_f32_16x16x32_bf16(ah, bh, acc[nt], 0, 0, 0);
            acc[nt] = __builtin_amdgcn_mfma_f32_16x16x32_bf16(ah, bl, acc[nt], 0, 0, 0);
            acc[nt] = __builtin_amdgcn_mfma_f32_16x16x32_bf16(al, bh, acc[nt], 0, 0, 0);
        }
    }

    float* yb = y + (size_t)b*CH*HWSZ + (size_t)h*WW + w0 + lw;
    #pragma unroll
    for (int nt=0; nt<2; ++nt) {
        #pragma unroll
        for (int i=0;i<4;++i) {
            int oc = nt*16 + lq*4 + i;
            yb[(size_t)oc*HWSZ] = lrelu_f(acc[nt][i] + bias[oc]);
        }
    }
}

extern "C" void kernel_launch(void* const* d_in, const int* in_sizes, int n_in,
                              void* d_out, int out_size, void* d_ws, size_t ws_size,
                              hipStream_t stream)
{
    (void)in_sizes; (void)n_in; (void)out_size;
    const float* short_fea = (const float*)d_in[0];
    const float* long_fea  = (const float*)d_in[1];
    const float* prev      = (const float*)d_in[2];
    const float* conv1_w   = (const float*)d_in[3];
    const float* conv1_b   = (const float*)d_in[4];
    const float* oc1_w     = (const float*)d_in[5];
    const float* oc1_b     = (const float*)d_in[6];
    const float* oc2_w     = (const float*)d_in[7];
    const float* oc2_b     = (const float*)d_in[8];
    const float* oc3_w     = (const float*)d_in[9];
    const float* oc3_b     = (const float*)d_in[10];
    const float* dow       = (const float*)d_in[11];
    const float* dob       = (const float*)d_in[12];
    const float* dcw       = (const float*)d_in[13];
    const float* dcb       = (const float*)d_in[14];

    float* out = (float*)d_out;                       // [2,32,256,256]
    float* off_out = out + (size_t)2*CH*HWSZ;         // [2,32,256,256]

    const int CROWS = 128;                             // val row-chunk
    size_t om_b   = (size_t)2*216*HWSZ*2;              // 56.6 MB (bf16)
    size_t cat_b  = (size_t)2*HWSZ*128*2;              // 33.6 MB (overlaps om)
    size_t t_b    = (size_t)2*HWSZ*64*2;               // 16.8 MB (overlaps om)
    size_t xo_b   = (size_t)2*HWSZ*32*2;               // 8.4 MB
    size_t val_b  = (size_t)2*144*CROWS*WW*4;          // 37.75 MB per array
    size_t wpk_b  = (size_t)9*14*64*8*2;
    size_t wo1_b  = (size_t)9*1*2*64*8*2;
    size_t wo2_b  = (size_t)9*2*2*64*8*2;
    size_t wo3_b  = (size_t)9*1*2*64*8*2;
    size_t wg_b   = (size_t)9*2*64*8*2;
    size_t needed = om_b + xo_b + 2*val_b + wpk_b + 2*(wo1_b+wo2_b+wo3_b) + 2*wg_b;

    if (ws_size >= needed && om_b >= cat_b + t_b) {
        char* p = (char*)d_ws;
        unsigned short* om = (unsigned short*)p;
        unsigned short* cat  = (unsigned short*)p;                 // inside om
        unsigned short* tbuf = (unsigned short*)(p + cat_b);       // inside om
        p += om_b;
        unsigned short* xqo = (unsigned short*)p;  p += xo_b;
        unsigned int* vhi = (unsigned int*)p;      p += val_b;
        unsigned int* vlo = (unsigned int*)p;      p += val_b;
        unsigned short* wpk = (unsigned short*)p;  p += wpk_b;
        unsigned short* wo1h = (unsigned short*)p; p += wo1_b;
        unsigned short* wo1l = (unsigned short*)p; p += wo1_b;
        unsigned short* wo2h = (unsigned short*)p; p += wo2_b;
        unsigned short* wo2l = (unsigned short*)p; p += wo2_b;
        unsigned short* wo3h = (unsigned short*)p; p += wo3_b;
        unsigned short* wo3l = (unsigned short*)p; p += wo3_b;
        unsigned short* wgh = (unsigned short*)p;  p += wg_b;
        unsigned short* wgl = (unsigned short*)p;

        pack_conv_hl<<<5, 256, 0, stream>>>(oc1_w, wo1h, wo1l, 9, 1);
        pack_conv_hl<<<9, 256, 0, stream>>>(oc2_w, wo2h, wo2l, 9, 2);
        pack_conv_hl<<<5, 256, 0, stream>>>(oc3_w, wo3h, wo3l, 9, 1);
        pack_w_bf16<<<32, 256, 0, stream>>>(dow, wpk);
        pack_wg<<<5, 256, 0, stream>>>(dcw, wgh, wgl);

        const int PIX_BLOCKS = (2*HWSZ)/256;   // 512
        const int CONV_BLOCKS = 2*HH*4;        // 2048

        conv1_fused<<<PIX_BLOCKS, 256, 0, stream>>>(short_fea, long_fea, conv1_w, conv1_b, tbuf);
        conv_mfma<9,1,true,false,true><<<CONV_BLOCKS, 256, 0, stream>>>(
            tbuf, wo1h, wo1l, oc1_b, cat, 128, 0, 64, nullptr);
        up2_hl<<<PIX_BLOCKS, 256, 0, stream>>>(prev, cat);
        conv_mfma<9,2,true,false,true><<<CONV_BLOCKS, 256, 0, stream>>>(
            cat, wo2h, wo2l, oc2_b, tbuf, 64, 0, 32, nullptr);
        conv_mfma<9,1,true,true,false><<<CONV_BLOCKS, 256, 0, stream>>>(
            tbuf, wo3h, wo3l, oc3_b, xqo, 32, 0, 0, off_out);

        // cat/tbuf dead; om (bf16) may be written.
        dcn_off_mfma<<<2*HH*4, 256, 0, stream>>>(xqo, wpk, dob, om, 0, HH);

        for (int r0 = 0; r0 < HH; r0 += CROWS) {
            dim3 gs(CROWS, 9, 2);   // 2304 blocks -> 9216 waves
            dcn_sample<<<gs, 256, 0, stream>>>(long_fea, om, vhi, vlo, r0, CROWS);
            dcn_gemm<<<2*CROWS*4, 256, 0, stream>>>(vhi, vlo, wgh, wgl, dcb, out, r0, CROWS);
        }
    } else {
        // fp32 fallback
        float* bufB = (float*)d_ws;
        float* bufU = bufB + (size_t)2*CH*HWSZ;
        float* om   = bufU + (size_t)2*CH*HWSZ;
        size_t used = (size_t)2 * 2*CH*HWSZ * sizeof(float);
        size_t avail = (ws_size > used) ? (ws_size - used) : 0;
        const int PIX_BLOCKS = (2*HWSZ)/256;

        conv1x1_kernel<<<PIX_BLOCKS, 256, 0, stream>>>(short_fea, long_fea, conv1_w, conv1_b, out);
        conv3x3_kernel<1><<<PIX_BLOCKS, 256, 0, stream>>>(out, nullptr, oc1_w, oc1_b, bufB, 1);
        up2_kernel<<<(2*CH*HWSZ)/256, 256, 0, stream>>>(prev, bufU);
        conv3x3_kernel<2><<<PIX_BLOCKS, 256, 0, stream>>>(bufB, bufU, oc2_w, oc2_b, out, 1);
        conv3x3_kernel<1><<<PIX_BLOCKS, 256, 0, stream>>>(out, nullptr, oc3_w, oc3_b, off_out, 1);

        size_t per_row = (size_t)216 * WW * sizeof(float);
        int rows_chunk = (int)(avail / per_row);
        if (rows_chunk < 1) rows_chunk = 1;
        if (rows_chunk > HH) rows_chunk = HH;
        for (int b=0;b<2;++b) {
            const float* offb = off_out + (size_t)b*CH*HWSZ;
            const float* lfb  = long_fea + (size_t)b*CH*HWSZ;
            float* outb = out + (size_t)b*CH*HWSZ;
            for (int r0=0;r0<HH;r0+=rows_chunk) {
                int rows = (HH - r0 < rows_chunk) ? (HH - r0) : rows_chunk;
                dim3 g1(rows, 9);
                dcn_off_kernel<<<g1, 256, 0, stream>>>(offb, dow, dob, om, r0, rows);
                dim3 g2f(rows, 2, 1);
                dcn_kernel<<<g2f, 256, 0, stream>>>(lfb, om, dcw, dcb, outb, r0, rows);
            }
        }
    }
}